// Round 11
// baseline (165.062 us; speedup 1.0000x reference)
//
#include <hip/hip_runtime.h>
#include <hip/hip_bf16.h>

// Problem constants: B=8, S=2048, E=768, HEAD=128
#define BB 8
#define SS 2048
#define EE 768
#define HH 128
#define MM (BB*SS)     // 16384
#define NQT 32         // 64-row q-tiles per batch
#define NCH 144        // chunks per batch: sum_{qt} ceil((qt+1)/4)

typedef __attribute__((ext_vector_type(8))) short bf16x8;
typedef __attribute__((ext_vector_type(8))) unsigned short ushort8;
typedef __attribute__((ext_vector_type(4))) float f32x4;

__device__ __forceinline__ unsigned short f2bf(float x) {
    unsigned int u = __float_as_uint(x);
    u += 0x7fff + ((u >> 16) & 1);   // RNE
    return (unsigned short)(u >> 16);
}
__device__ __forceinline__ float bf2f(unsigned short h) {
    return __uint_as_float(((unsigned int)h) << 16);
}
// async global->LDS, 16B per lane; LDS dest = wave-uniform base + lane*16
__device__ __forceinline__ void gld16(const unsigned short* g, unsigned short* l) {
    __builtin_amdgcn_global_load_lds(
        (const __attribute__((address_space(1))) unsigned int*)g,
        (__attribute__((address_space(3))) unsigned int*)l, 16, 0, 0);
}

// ---------------------------------------------------------------------------
// cvt: Xb = bf16(X * mask)  [16384][768];  Wb = bf16([Wq;Wk;Wv]) [384][768]
// grid 1536 (X, grid-stride x8) + 288 (W), 256 thr. HBM-bound (~13us floor).
// ---------------------------------------------------------------------------
__global__ __launch_bounds__(256)
void cvt(const float* __restrict__ X, const float* __restrict__ mask,
         const float* __restrict__ Wq, const float* __restrict__ Wk,
         const float* __restrict__ Wv,
         unsigned short* __restrict__ Xb, unsigned short* __restrict__ Wb)
{
    const int bid = blockIdx.x;
    if (bid < 1536) {
        int base = bid * 256 + threadIdx.x;          // float4 index
#pragma unroll
        for (int it = 0; it < 8; it++) {
            int idx = base + it * 393216;            // < 3145728
            int row = idx / 192;                     // 192 float4 per row
            int i4  = idx * 4;
            float mk = mask[row];
            float4 v = *(const float4*)(X + i4);
            ushort4 o;
            o.x = f2bf(v.x * mk); o.y = f2bf(v.y * mk);
            o.z = f2bf(v.z * mk); o.w = f2bf(v.w * mk);
            *(ushort4*)(Xb + i4) = o;
        }
    } else {
        int i4 = ((bid - 1536) * 256 + threadIdx.x) * 4;   // < 294912
        const float* src; int off;
        if (i4 < 98304)       { src = Wq; off = i4; }
        else if (i4 < 196608) { src = Wk; off = i4 - 98304; }
        else                  { src = Wv; off = i4 - 196608; }
        float4 v = *(const float4*)(src + off);
        ushort4 o;
        o.x = f2bf(v.x); o.y = f2bf(v.y); o.z = f2bf(v.z); o.w = f2bf(v.w);
        *(ushort4*)(Wb + i4) = o;
    }
}

// staging for one 64-wide k-slice of A (64 rows) + B (128 rows) into buf
__device__ __forceinline__ void stage_gemm(const unsigned short* __restrict__ Xb,
                                           const unsigned short* __restrict__ Wb,
                                           int m0, int n0g, int k0, int t, int wub,
                                           unsigned short* buf)
{
    // A: 64 rows x 8 chunks (2 passes) -> buf[0..4095]
#pragma unroll
    for (int i = 0; i < 2; i++) {
        int cg = i * 256 + t;
        int row = cg >> 3, slot = cg & 7;
        int cc = slot ^ (row & 7);
        gld16(Xb + (size_t)(m0 + row) * EE + k0 + cc * 8, buf + i * 2048 + wub);
    }
    // B: 128 rows x 8 chunks (4 passes) -> buf[4096..12287]
#pragma unroll
    for (int i = 0; i < 4; i++) {
        int cg = i * 256 + t;
        int row = cg >> 3, slot = cg & 7;
        int cc = slot ^ (row & 7);
        gld16(Wb + (size_t)(n0g + row) * EE + k0 + cc * 8, buf + 4096 + i * 2048 + wub);
    }
}

// ---------------------------------------------------------------------------
// QKV GEMM — R8 bytes (measured best): R2 core + T3 2-phase async pipeline.
//   prologue: STAGE(buf0, k=0); vmcnt(0); barrier
//   loop: STAGE(buf^1, k+1) -> compute(buf) -> vmcnt(0) + raw s_barrier
// LDS 2x24 KB = 48 KB -> 3 blocks/CU. VGPR unchanged (no data regs).
// XCD decode: xcd = flat&7 owns 32 consecutive m-tiles x all 3 mats.
// mat 2 (V): LDS-bounce transpose epilogue.
// ---------------------------------------------------------------------------
__global__ __launch_bounds__(256, 3)
void qkv_gemm(const unsigned short* __restrict__ Xb, const unsigned short* __restrict__ Wb,
              unsigned short* __restrict__ Q, unsigned short* __restrict__ K,
              unsigned short* __restrict__ Vt)
{
    const int flat = blockIdx.x;          // 768
    const int xcd  = flat & 7;
    const int k2   = flat >> 3;           // 96 per XCD
    const int mat  = k2 % 3;
    const int y    = xcd * 32 + k2 / 3;   // m-tile 0..255, 32 consecutive per XCD
    const int m0   = y * 64;
    const int n0g  = mat * 128;           // row offset into Wb [384][768]

    __shared__ __align__(16) unsigned short SM[2][12288];  // 48 KB double buffer

    const int t = threadIdx.x, lane = t & 63;
    const int quad = lane >> 4, l16 = lane & 15;
    const int wave = t >> 6;
    const int wn = wave * 32;
    const int wub = (t & 192) * 8;           // wave-uniform base (shorts)

    f32x4 acc[4][2];
#pragma unroll
    for (int i = 0; i < 4; i++)
#pragma unroll
        for (int j = 0; j < 2; j++) acc[i][j] = (f32x4)0.0f;

    // prologue: stage tile 0, full drain once
    stage_gemm(Xb, Wb, m0, n0g, 0, t, wub, SM[0]);
    asm volatile("s_waitcnt vmcnt(0)" ::: "memory");
    __builtin_amdgcn_s_barrier();
    __builtin_amdgcn_sched_barrier(0);

    int cur = 0;
    for (int ks = 0; ks < 12; ks++) {
        // issue next tile's loads; they land under this tile's compute
        if (ks + 1 < 12)
            stage_gemm(Xb, Wb, m0, n0g, (ks + 1) * 64, t, wub, SM[cur ^ 1]);

        const unsigned short* As = SM[cur];
        const unsigned short* Bs = SM[cur] + 4096;
#pragma unroll
        for (int kk = 0; kk < 2; kk++) {
            bf16x8 a[4], b[2];
#pragma unroll
            for (int i = 0; i < 4; i++) {
                int row = i * 16 + l16;
                a[i] = *(const bf16x8*)&As[row * 64 + (((kk * 4 + quad) ^ (l16 & 7)) << 3)];
            }
#pragma unroll
            for (int j = 0; j < 2; j++) {
                int row = wn + j * 16 + l16;
                b[j] = *(const bf16x8*)&Bs[row * 64 + (((kk * 4 + quad) ^ (l16 & 7)) << 3)];
            }
            __builtin_amdgcn_s_setprio(1);
#pragma unroll
            for (int i = 0; i < 4; i++)
#pragma unroll
                for (int j = 0; j < 2; j++)
                    acc[i][j] = __builtin_amdgcn_mfma_f32_16x16x32_bf16(a[i], b[j], acc[i][j], 0, 0, 0);
            __builtin_amdgcn_s_setprio(0);
        }

        // drain next-tile loads (they've had the compute phase to land) + sync
        asm volatile("s_waitcnt vmcnt(0)" ::: "memory");
        __builtin_amdgcn_s_barrier();
        __builtin_amdgcn_sched_barrier(0);
        cur ^= 1;
    }

    if (mat < 2) {
        unsigned short* dst = (mat == 0) ? Q : K;
#pragma unroll
        for (int i = 0; i < 4; i++)
#pragma unroll
            for (int r = 0; r < 4; r++) {
                int m = m0 + i * 16 + quad * 4 + r;
#pragma unroll
                for (int j = 0; j < 2; j++)
                    dst[(size_t)m * HH + wn + j * 16 + l16] = f2bf(acc[i][j][r]);
            }
    } else {
        // transpose 64(tok) x 128(h) through LDS (reuse SM[0]): SM0[h][tok]
        unsigned short* T = SM[0];
        __syncthreads();
#pragma unroll
        for (int i = 0; i < 4; i++)
#pragma unroll
            for (int r = 0; r < 4; r++) {
                int tok = i * 16 + quad * 4 + r;
                int cc = tok >> 3, w = tok & 7;
#pragma unroll
                for (int j = 0; j < 2; j++) {
                    int h = wn + j * 16 + l16;
                    T[h * 64 + ((cc ^ (h & 7)) << 3) + w] = f2bf(acc[i][j][r]);
                }
            }
        __syncthreads();
        const int bidx = m0 >> 11, mloc = m0 & 2047;
#pragma unroll
        for (int i = 0; i < 4; i++) {
            int cg = i * 256 + t;
            int h = cg >> 3, cc = cg & 7;
            ulonglong2 v = *(const ulonglong2*)&T[h * 64 + ((cc ^ (h & 7)) << 3)];
            *(ulonglong2*)&Vt[((size_t)bidx * HH + h) * SS + mloc + cc * 8] = v;
        }
    }
}

// ---------------------------------------------------------------------------
// Flash attention — R10 skeleton (gld16 linear+swizzled K/V staging, T13
// defer-max, b=f&7 XCD pinning, heavy-first, setprio).
// NEW (only change): Ps padded-72 -> 64-col XOR-chunk swizzle. Bank profile
// is equivalent (verified: read 8 lanes/4-bank group, write 4/bank — same as
// the 72-pad layout), but LDS drops 41984 -> 40960 B EXACTLY: 160KB/CU div 40KB
// = 4 blocks/CU (was 3). +33% waves/SIMD on a latency-bound kernel.
// __launch_bounds__(256,4) caps VGPR at 128 (skeleton uses ~84 — safe).
// Grid 1152 = 1024-slot round + light tail (heavy-first puts <=3-tile chunks
// in the tail). If the 4th block doesn't fit reserved LDS: exactly neutral.
// ---------------------------------------------------------------------------
__global__ __launch_bounds__(256, 4)
void attn(const unsigned short* __restrict__ Q, const unsigned short* __restrict__ K,
          const unsigned short* __restrict__ Vt,
          unsigned short* __restrict__ Po, float* __restrict__ Pm, float* __restrict__ Pl)
{
    const int f = blockIdx.x;
    const int b = f & 7;                 // batch == XCD
    const int c = 143 - (f >> 3);        // heavy chunks (large g) start first
    // decode chunk id -> (qt, ch): cumulative chunks before group g = 2g(g+1)
    int g = (int)((__builtin_sqrtf(2.0f * c + 1.0f) - 1.0f) * 0.5f);
    while (2 * (g + 1) * (g + 2) <= c) g++;
    while (2 * g * (g + 1) > c) g--;
    const int idx = c - 2 * g * (g + 1);
    const int qt = 4 * g + idx / (g + 1);
    const int ch = idx % (g + 1);
    const int q0 = qt * 64;
    const int kt0 = ch * 4;
    const int kt1 = min(kt0 + 4, qt + 1);

    const int t = threadIdx.x, lane = t & 63;
    const int wave = t >> 6, quad = lane >> 4, l16 = lane & 15;
    const int wub = (t & 192) * 8;       // wave-uniform base (shorts)

    __shared__ __align__(16) unsigned short Ks[64 * 128];   // linear, swz-read
    __shared__ __align__(16) unsigned short Vs[128 * 64];   // linear, swz-read
    __shared__ __align__(16) unsigned short Ps[4][1024];    // per-wave, swizzled
    // Ps layout: element (row,col) at row*64 + ((col>>3)^(row&7))*8 + (col&7)

    bf16x8 qf[4];
    {
        const unsigned short* qrow = Q + (size_t)(b * SS + q0 + wave * 16 + l16) * HH;
#pragma unroll
        for (int dd = 0; dd < 4; dd++)
            qf[dd] = *(const bf16x8*)(qrow + dd * 32 + quad * 8);
    }

    f32x4 o[8];
#pragma unroll
    for (int j = 0; j < 8; j++) o[j] = (f32x4)0.0f;
    f32x4 o9 = (f32x4)0.0f;                  // row-sum accumulator (l)
    float mrow[4];
#pragma unroll
    for (int r = 0; r < 4; r++) mrow[r] = -1e30f;

    const float sscale = 0.08838834764831845f * 1.4426950408889634f;  // 1/sqrt(128)*log2e

    bf16x8 ones;
    {
        short e = (l16 == 0) ? (short)0x3F80 : (short)0;
        ones = (bf16x8){e, e, e, e, e, e, e, e};
    }

    for (int kt = kt0; kt < kt1; kt++) {
        const int k0 = kt * 64;
        __syncthreads();
        // stage K-tile 64x128 via gld16 (16 chunks/row, src slot^(row&7))
#pragma unroll
        for (int it = 0; it < 4; it++) {
            int n = it * 256 + t;
            int row = n >> 4, slot = n & 15;
            gld16(K + (size_t)(b * SS + k0 + row) * HH + ((slot ^ (row & 7)) << 3),
                  Ks + it * 2048 + wub);
        }
        // stage V^T-tile 128x64 via gld16 (8 chunks/row)
#pragma unroll
        for (int it = 0; it < 4; it++) {
            int n = it * 256 + t;
            int row = n >> 3, slot = n & 7;
            gld16(Vt + ((size_t)b * HH + row) * SS + k0 + ((slot ^ (row & 7)) << 3),
                  Vs + it * 2048 + wub);
        }
        __syncthreads();

        // S = Q K^T
        f32x4 s[4];
#pragma unroll
        for (int ct = 0; ct < 4; ct++) s[ct] = (f32x4)0.0f;
        __builtin_amdgcn_s_setprio(1);
#pragma unroll
        for (int dd = 0; dd < 4; dd++) {
#pragma unroll
            for (int ct = 0; ct < 4; ct++) {
                int krow = ct * 16 + l16;
                bf16x8 kfr = *(const bf16x8*)&Ks[krow * 128 + (((dd * 4 + quad) ^ (l16 & 7)) << 3)];
                s[ct] = __builtin_amdgcn_mfma_f32_16x16x32_bf16(qf[dd], kfr, s[ct], 0, 0, 0);
            }
        }
        __builtin_amdgcn_s_setprio(0);

        const bool diag = (kt == qt);
        float sv[4][4];
#pragma unroll
        for (int ct = 0; ct < 4; ct++) {
            int col = k0 + ct * 16 + l16;
#pragma unroll
            for (int r = 0; r < 4; r++) {
                float v = s[ct][r] * sscale;
                if (diag) {
                    int row = q0 + wave * 16 + quad * 4 + r;
                    if (col > row) v = -1e30f;
                }
                sv[ct][r] = v;
            }
        }

        // tile row-max
        float vmax[4];
#pragma unroll
        for (int r = 0; r < 4; r++) {
            float v = fmaxf(fmaxf(sv[0][r], sv[1][r]), fmaxf(sv[2][r], sv[3][r]));
            v = fmaxf(v, __shfl_xor(v, 1));
            v = fmaxf(v, __shfl_xor(v, 2));
            v = fmaxf(v, __shfl_xor(v, 4));
            v = fmaxf(v, __shfl_xor(v, 8));
            vmax[r] = v;
        }
        // T13 defer-max: rescale only when some row grew by > 8 log2-units.
        float growth = fmaxf(fmaxf(vmax[0] - mrow[0], vmax[1] - mrow[1]),
                             fmaxf(vmax[2] - mrow[2], vmax[3] - mrow[3]));
        if (!__all(growth <= 8.0f)) {
            float alpha[4];
#pragma unroll
            for (int r = 0; r < 4; r++) {
                float mnew = fmaxf(mrow[r], vmax[r]);
                alpha[r] = exp2f(mrow[r] - mnew);
                mrow[r]  = mnew;
            }
#pragma unroll
            for (int j = 0; j < 8; j++)
#pragma unroll
                for (int r = 0; r < 4; r++) o[j][r] *= alpha[r];
#pragma unroll
            for (int r = 0; r < 4; r++) o9[r] *= alpha[r];
        }
        // P -> wave-private swizzled LDS: (row, col=ct*16+l16), chunk=ct*2+(l16>>3)
#pragma unroll
        for (int ct = 0; ct < 4; ct++) {
#pragma unroll
            for (int r = 0; r < 4; r++) {
                float p = exp2f(sv[ct][r] - mrow[r]);
                int row = quad * 4 + r;
                Ps[wave][row * 64 + (((ct * 2 + (l16 >> 3)) ^ (row & 7)) << 3) + (l16 & 7)] = f2bf(p);
            }
        }

        // PV + row-sum column (read logical chunk kk*4+quad of row l16)
        __builtin_amdgcn_s_setprio(1);
#pragma unroll
        for (int kk = 0; kk < 2; kk++) {
            bf16x8 pf = *(const bf16x8*)&Ps[wave][l16 * 64 + (((kk * 4 + quad) ^ (l16 & 7)) << 3)];
#pragma unroll
            for (int j = 0; j < 8; j++) {
                int vrow = j * 16 + l16;
                bf16x8 vf = *(const bf16x8*)&Vs[vrow * 64 + (((kk * 4 + quad) ^ (l16 & 7)) << 3)];
                o[j] = __builtin_amdgcn_mfma_f32_16x16x32_bf16(pf, vf, o[j], 0, 0, 0);
            }
            o9 = __builtin_amdgcn_mfma_f32_16x16x32_bf16(pf, ones, o9, 0, 0, 0);
        }
        __builtin_amdgcn_s_setprio(0);
    }

    // store partials: Po permuted layout [row][l16][j] -> 16B/lane full-line stores
    const size_t pidx = (size_t)b * NCH + c;
    const size_t pobase = pidx * (64 * 128);
    const size_t mbase  = pidx * 64;
#pragma unroll
    for (int r = 0; r < 4; r++) {
        int row = wave * 16 + quad * 4 + r;
        if (l16 == 0) { Pm[mbase + row] = mrow[r]; Pl[mbase + row] = o9[r]; }
        ushort8 val;
#pragma unroll
        for (int j = 0; j < 8; j++) val[j] = f2bf(o[j][r]);
        *(ushort8*)&Po[pobase + (size_t)row * 128 + l16 * 8] = val;
    }
}

// ---------------------------------------------------------------------------
// Combine n_ch(qt) <= 8 partials per (b,qt). grid (32, 8, 2), 32 q-rows/block.
// 16B ushort8 loads (permuted Po layout), dynamic s < n_ch loop. (R2 version.)
// ---------------------------------------------------------------------------
__global__ __launch_bounds__(256)
void combine(const unsigned short* __restrict__ Po, const float* __restrict__ Pm,
             const float* __restrict__ Pl, float* __restrict__ Out)
{
    const int qt = blockIdx.x, b = blockIdx.y, half = blockIdx.z;  // rows half*32..
    const int g = qt >> 2;
    const int n_ch = g + 1;
    const int cbase = 2 * g * (g + 1) + (qt - 4 * g) * (g + 1);
    const size_t p0 = (size_t)b * NCH + cbase;
    const int t = threadIdx.x;

    __shared__ float sw[8][32];    // [s][local row]
    __shared__ float sinv[32];

    if (t < 32) {
        int grow = half * 32 + t;
        float ms = -1e30f;
        for (int s = 0; s < n_ch; s++)
            ms = fmaxf(ms, Pm[(p0 + s) * 64 + grow]);
        float lsum = 0.0f;
        for (int s = 0; s < n_ch; s++) {
            float w = exp2f(Pm[(p0 + s) * 64 + grow] - ms);   // reload: L1-hot
            sw[s][t] = w;
            lsum += w * Pl[(p0 + s) * 64 + grow];
        }
        sinv[t] = 1.0f / lsum;
    }
    __syncthreads();

    float acc[2][8];
#pragma unroll
    for (int pass = 0; pass < 2; pass++)
#pragma unroll
        for (int j = 0; j < 8; j++) acc[pass][j] = 0.0f;

    for (int s = 0; s < n_ch; s++) {
        const size_t sbase = (p0 + s) * 8192;
#pragma unroll
        for (int pass = 0; pass < 2; pass++) {
            int cell = pass * 256 + t;
            int row = cell >> 4, l16g = cell & 15;
            int grow = half * 32 + row;
            float w = sw[s][row];
            ushort8 v = *(const ushort8*)&Po[sbase + (size_t)grow * 128 + l16g * 8];
#pragma unroll
            for (int j = 0; j < 8; j++) acc[pass][j] += w * bf2f(v[j]);
        }
    }

#pragma unroll
    for (int pass = 0; pass < 2; pass++) {
        int cell = pass * 256 + t;
        int row = cell >> 4, l16g = cell & 15;
        int grow = half * 32 + row;
        float inv = sinv[row];
        // Po slot (l16g, j) holds logical head-col j*16 + l16g
#pragma unroll
        for (int j = 0; j < 8; j++)
            Out[((size_t)b * SS + qt * 64 + grow) * HH + j * 16 + l16g] = acc[pass][j] * inv;
    }
}

extern "C" void kernel_launch(void* const* d_in, const int* in_sizes, int n_in,
                              void* d_out, int out_size, void* d_ws, size_t ws_size,
                              hipStream_t stream) {
    const float* X    = (const float*)d_in[0];
    const float* mask = (const float*)d_in[1];
    const float* Wq   = (const float*)d_in[2];
    const float* Wk   = (const float*)d_in[3];
    const float* Wv   = (const float*)d_in[4];

    char* ws = (char*)d_ws;
    // region A: Xb (25.2 MB) consumed by qkv_gemm, then reused as Po (18.9 MB)
    unsigned short* Xb = (unsigned short*)ws;
    unsigned short* Po = (unsigned short*)ws;
    ws += (size_t)MM * EE * 2;                                   // 25.17 MB
    unsigned short* Wb = (unsigned short*)ws; ws += (size_t)384 * EE * 2;
    unsigned short* Q  = (unsigned short*)ws; ws += (size_t)MM * HH * 2;
    unsigned short* Kb = (unsigned short*)ws; ws += (size_t)MM * HH * 2;
    unsigned short* Vt = (unsigned short*)ws; ws += (size_t)MM * HH * 2;
    float* Pm = (float*)ws; ws += (size_t)BB * NCH * 64 * 4;
    float* Pl = (float*)ws;

    cvt<<<1536 + 288, 256, 0, stream>>>(X, mask, Wq, Wk, Wv, Xb, Wb);
    qkv_gemm<<<768, 256, 0, stream>>>(Xb, Wb, Q, Kb, Vt);
    attn<<<1152, 256, 0, stream>>>(Q, Kb, Vt, Po, Pm, Pl);
    combine<<<dim3(NQT, BB, 2), 256, 0, stream>>>(Po, Pm, Pl, (float*)d_out);
}

// Round 12
// 148.108 us; speedup vs baseline: 1.1145x; 1.1145x over previous
//
#include <hip/hip_runtime.h>
#include <hip/hip_bf16.h>

// Problem constants: B=8, S=2048, E=768, HEAD=128
#define BB 8
#define SS 2048
#define EE 768
#define HH 128
#define MM (BB*SS)     // 16384
#define NQT 32         // 64-row q-tiles per batch
#define NCH 144        // chunks per batch: sum_{qt} ceil((qt+1)/4)

typedef __attribute__((ext_vector_type(8))) short bf16x8;
typedef __attribute__((ext_vector_type(8))) unsigned short ushort8;
typedef __attribute__((ext_vector_type(4))) float f32x4;

__device__ __forceinline__ unsigned short f2bf(float x) {
    unsigned int u = __float_as_uint(x);
    u += 0x7fff + ((u >> 16) & 1);   // RNE
    return (unsigned short)(u >> 16);
}
__device__ __forceinline__ float bf2f(unsigned short h) {
    return __uint_as_float(((unsigned int)h) << 16);
}
// async global->LDS, 16B per lane; LDS dest = wave-uniform base + lane*16
__device__ __forceinline__ void gld16(const unsigned short* g, unsigned short* l) {
    __builtin_amdgcn_global_load_lds(
        (const __attribute__((address_space(1))) unsigned int*)g,
        (__attribute__((address_space(3))) unsigned int*)l, 16, 0, 0);
}

// ---------------------------------------------------------------------------
// cvt: Xb = bf16(X * mask)  [16384][768];  Wb = bf16([Wq;Wk;Wv]) [384][768]
// grid 1536 (X, grid-stride x8) + 288 (W), 256 thr. HBM-bound (~13us floor).
// ---------------------------------------------------------------------------
__global__ __launch_bounds__(256)
void cvt(const float* __restrict__ X, const float* __restrict__ mask,
         const float* __restrict__ Wq, const float* __restrict__ Wk,
         const float* __restrict__ Wv,
         unsigned short* __restrict__ Xb, unsigned short* __restrict__ Wb)
{
    const int bid = blockIdx.x;
    if (bid < 1536) {
        int base = bid * 256 + threadIdx.x;          // float4 index
#pragma unroll
        for (int it = 0; it < 8; it++) {
            int idx = base + it * 393216;            // < 3145728
            int row = idx / 192;                     // 192 float4 per row
            int i4  = idx * 4;
            float mk = mask[row];
            float4 v = *(const float4*)(X + i4);
            ushort4 o;
            o.x = f2bf(v.x * mk); o.y = f2bf(v.y * mk);
            o.z = f2bf(v.z * mk); o.w = f2bf(v.w * mk);
            *(ushort4*)(Xb + i4) = o;
        }
    } else {
        int i4 = ((bid - 1536) * 256 + threadIdx.x) * 4;   // < 294912
        const float* src; int off;
        if (i4 < 98304)       { src = Wq; off = i4; }
        else if (i4 < 196608) { src = Wk; off = i4 - 98304; }
        else                  { src = Wv; off = i4 - 196608; }
        float4 v = *(const float4*)(src + off);
        ushort4 o;
        o.x = f2bf(v.x); o.y = f2bf(v.y); o.z = f2bf(v.z); o.w = f2bf(v.w);
        *(ushort4*)(Wb + i4) = o;
    }
}

// staging for one 64-wide k-slice of A (64 rows) + B (128 rows) into buf
__device__ __forceinline__ void stage_gemm(const unsigned short* __restrict__ Xb,
                                           const unsigned short* __restrict__ Wb,
                                           int m0, int n0g, int k0, int t, int wub,
                                           unsigned short* buf)
{
    // A: 64 rows x 8 chunks (2 passes) -> buf[0..4095]
#pragma unroll
    for (int i = 0; i < 2; i++) {
        int cg = i * 256 + t;
        int row = cg >> 3, slot = cg & 7;
        int cc = slot ^ (row & 7);
        gld16(Xb + (size_t)(m0 + row) * EE + k0 + cc * 8, buf + i * 2048 + wub);
    }
    // B: 128 rows x 8 chunks (4 passes) -> buf[4096..12287]
#pragma unroll
    for (int i = 0; i < 4; i++) {
        int cg = i * 256 + t;
        int row = cg >> 3, slot = cg & 7;
        int cc = slot ^ (row & 7);
        gld16(Wb + (size_t)(n0g + row) * EE + k0 + cc * 8, buf + 4096 + i * 2048 + wub);
    }
}

// ---------------------------------------------------------------------------
// QKV GEMM — R8 bytes (measured best): R2 core + T3 2-phase async pipeline.
//   prologue: STAGE(buf0, k=0); vmcnt(0); barrier
//   loop: STAGE(buf^1, k+1) -> compute(buf) -> vmcnt(0) + raw s_barrier
// LDS 2x24 KB = 48 KB -> 3 blocks/CU. VGPR unchanged (no data regs).
// XCD decode: xcd = flat&7 owns 32 consecutive m-tiles x all 3 mats.
// mat 2 (V): LDS-bounce transpose epilogue.
// ---------------------------------------------------------------------------
__global__ __launch_bounds__(256, 3)
void qkv_gemm(const unsigned short* __restrict__ Xb, const unsigned short* __restrict__ Wb,
              unsigned short* __restrict__ Q, unsigned short* __restrict__ K,
              unsigned short* __restrict__ Vt)
{
    const int flat = blockIdx.x;          // 768
    const int xcd  = flat & 7;
    const int k2   = flat >> 3;           // 96 per XCD
    const int mat  = k2 % 3;
    const int y    = xcd * 32 + k2 / 3;   // m-tile 0..255, 32 consecutive per XCD
    const int m0   = y * 64;
    const int n0g  = mat * 128;           // row offset into Wb [384][768]

    __shared__ __align__(16) unsigned short SM[2][12288];  // 48 KB double buffer

    const int t = threadIdx.x, lane = t & 63;
    const int quad = lane >> 4, l16 = lane & 15;
    const int wave = t >> 6;
    const int wn = wave * 32;
    const int wub = (t & 192) * 8;           // wave-uniform base (shorts)

    f32x4 acc[4][2];
#pragma unroll
    for (int i = 0; i < 4; i++)
#pragma unroll
        for (int j = 0; j < 2; j++) acc[i][j] = (f32x4)0.0f;

    // prologue: stage tile 0, full drain once
    stage_gemm(Xb, Wb, m0, n0g, 0, t, wub, SM[0]);
    asm volatile("s_waitcnt vmcnt(0)" ::: "memory");
    __builtin_amdgcn_s_barrier();
    __builtin_amdgcn_sched_barrier(0);

    int cur = 0;
    for (int ks = 0; ks < 12; ks++) {
        // issue next tile's loads; they land under this tile's compute
        if (ks + 1 < 12)
            stage_gemm(Xb, Wb, m0, n0g, (ks + 1) * 64, t, wub, SM[cur ^ 1]);

        const unsigned short* As = SM[cur];
        const unsigned short* Bs = SM[cur] + 4096;
#pragma unroll
        for (int kk = 0; kk < 2; kk++) {
            bf16x8 a[4], b[2];
#pragma unroll
            for (int i = 0; i < 4; i++) {
                int row = i * 16 + l16;
                a[i] = *(const bf16x8*)&As[row * 64 + (((kk * 4 + quad) ^ (l16 & 7)) << 3)];
            }
#pragma unroll
            for (int j = 0; j < 2; j++) {
                int row = wn + j * 16 + l16;
                b[j] = *(const bf16x8*)&Bs[row * 64 + (((kk * 4 + quad) ^ (l16 & 7)) << 3)];
            }
            __builtin_amdgcn_s_setprio(1);
#pragma unroll
            for (int i = 0; i < 4; i++)
#pragma unroll
                for (int j = 0; j < 2; j++)
                    acc[i][j] = __builtin_amdgcn_mfma_f32_16x16x32_bf16(a[i], b[j], acc[i][j], 0, 0, 0);
            __builtin_amdgcn_s_setprio(0);
        }

        // drain next-tile loads (they've had the compute phase to land) + sync
        asm volatile("s_waitcnt vmcnt(0)" ::: "memory");
        __builtin_amdgcn_s_barrier();
        __builtin_amdgcn_sched_barrier(0);
        cur ^= 1;
    }

    if (mat < 2) {
        unsigned short* dst = (mat == 0) ? Q : K;
#pragma unroll
        for (int i = 0; i < 4; i++)
#pragma unroll
            for (int r = 0; r < 4; r++) {
                int m = m0 + i * 16 + quad * 4 + r;
#pragma unroll
                for (int j = 0; j < 2; j++)
                    dst[(size_t)m * HH + wn + j * 16 + l16] = f2bf(acc[i][j][r]);
            }
    } else {
        // transpose 64(tok) x 128(h) through LDS (reuse SM[0]): SM0[h][tok]
        unsigned short* T = SM[0];
        __syncthreads();
#pragma unroll
        for (int i = 0; i < 4; i++)
#pragma unroll
            for (int r = 0; r < 4; r++) {
                int tok = i * 16 + quad * 4 + r;
                int cc = tok >> 3, w = tok & 7;
#pragma unroll
                for (int j = 0; j < 2; j++) {
                    int h = wn + j * 16 + l16;
                    T[h * 64 + ((cc ^ (h & 7)) << 3) + w] = f2bf(acc[i][j][r]);
                }
            }
        __syncthreads();
        const int bidx = m0 >> 11, mloc = m0 & 2047;
#pragma unroll
        for (int i = 0; i < 4; i++) {
            int cg = i * 256 + t;
            int h = cg >> 3, cc = cg & 7;
            ulonglong2 v = *(const ulonglong2*)&T[h * 64 + ((cc ^ (h & 7)) << 3)];
            *(ulonglong2*)&Vt[((size_t)bidx * HH + h) * SS + mloc + cc * 8] = v;
        }
    }
}

// ---------------------------------------------------------------------------
// Flash attention — R10 skeleton + Ps 64-col XOR-chunk swizzle (LDS 40960 B:
// 4 blocks/CU now fit by LDS — 4 x 40960 = 160 KB exactly).
// FIX of R11: __launch_bounds__ back to (256,3). R11's (256,4) FORCED the
// allocator to 64 VGPR -> ~20 MB spill/dispatch, attn 50 us. (256,3) only
// guarantees a minimum; with natural VGPR (~84-128) the scheduler may still
// place the 4th block per CU, and if VGPR >128 we gracefully match R10.
// gld16 linear+swizzled K/V staging, T13 defer-max, b=f&7 XCD pinning,
// heavy-first, setprio. grid 1152.
// ---------------------------------------------------------------------------
__global__ __launch_bounds__(256, 3)
void attn(const unsigned short* __restrict__ Q, const unsigned short* __restrict__ K,
          const unsigned short* __restrict__ Vt,
          unsigned short* __restrict__ Po, float* __restrict__ Pm, float* __restrict__ Pl)
{
    const int f = blockIdx.x;
    const int b = f & 7;                 // batch == XCD
    const int c = 143 - (f >> 3);        // heavy chunks (large g) start first
    // decode chunk id -> (qt, ch): cumulative chunks before group g = 2g(g+1)
    int g = (int)((__builtin_sqrtf(2.0f * c + 1.0f) - 1.0f) * 0.5f);
    while (2 * (g + 1) * (g + 2) <= c) g++;
    while (2 * g * (g + 1) > c) g--;
    const int idx = c - 2 * g * (g + 1);
    const int qt = 4 * g + idx / (g + 1);
    const int ch = idx % (g + 1);
    const int q0 = qt * 64;
    const int kt0 = ch * 4;
    const int kt1 = min(kt0 + 4, qt + 1);

    const int t = threadIdx.x, lane = t & 63;
    const int wave = t >> 6, quad = lane >> 4, l16 = lane & 15;
    const int wub = (t & 192) * 8;       // wave-uniform base (shorts)

    __shared__ __align__(16) unsigned short Ks[64 * 128];   // linear, swz-read
    __shared__ __align__(16) unsigned short Vs[128 * 64];   // linear, swz-read
    __shared__ __align__(16) unsigned short Ps[4][1024];    // per-wave, swizzled
    // Ps layout: element (row,col) at row*64 + ((col>>3)^(row&7))*8 + (col&7)

    bf16x8 qf[4];
    {
        const unsigned short* qrow = Q + (size_t)(b * SS + q0 + wave * 16 + l16) * HH;
#pragma unroll
        for (int dd = 0; dd < 4; dd++)
            qf[dd] = *(const bf16x8*)(qrow + dd * 32 + quad * 8);
    }

    f32x4 o[8];
#pragma unroll
    for (int j = 0; j < 8; j++) o[j] = (f32x4)0.0f;
    f32x4 o9 = (f32x4)0.0f;                  // row-sum accumulator (l)
    float mrow[4];
#pragma unroll
    for (int r = 0; r < 4; r++) mrow[r] = -1e30f;

    const float sscale = 0.08838834764831845f * 1.4426950408889634f;  // 1/sqrt(128)*log2e

    bf16x8 ones;
    {
        short e = (l16 == 0) ? (short)0x3F80 : (short)0;
        ones = (bf16x8){e, e, e, e, e, e, e, e};
    }

    for (int kt = kt0; kt < kt1; kt++) {
        const int k0 = kt * 64;
        __syncthreads();
        // stage K-tile 64x128 via gld16 (16 chunks/row, src slot^(row&7))
#pragma unroll
        for (int it = 0; it < 4; it++) {
            int n = it * 256 + t;
            int row = n >> 4, slot = n & 15;
            gld16(K + (size_t)(b * SS + k0 + row) * HH + ((slot ^ (row & 7)) << 3),
                  Ks + it * 2048 + wub);
        }
        // stage V^T-tile 128x64 via gld16 (8 chunks/row)
#pragma unroll
        for (int it = 0; it < 4; it++) {
            int n = it * 256 + t;
            int row = n >> 3, slot = n & 7;
            gld16(Vt + ((size_t)b * HH + row) * SS + k0 + ((slot ^ (row & 7)) << 3),
                  Vs + it * 2048 + wub);
        }
        __syncthreads();

        // S = Q K^T
        f32x4 s[4];
#pragma unroll
        for (int ct = 0; ct < 4; ct++) s[ct] = (f32x4)0.0f;
        __builtin_amdgcn_s_setprio(1);
#pragma unroll
        for (int dd = 0; dd < 4; dd++) {
#pragma unroll
            for (int ct = 0; ct < 4; ct++) {
                int krow = ct * 16 + l16;
                bf16x8 kfr = *(const bf16x8*)&Ks[krow * 128 + (((dd * 4 + quad) ^ (l16 & 7)) << 3)];
                s[ct] = __builtin_amdgcn_mfma_f32_16x16x32_bf16(qf[dd], kfr, s[ct], 0, 0, 0);
            }
        }
        __builtin_amdgcn_s_setprio(0);

        const bool diag = (kt == qt);
        float sv[4][4];
#pragma unroll
        for (int ct = 0; ct < 4; ct++) {
            int col = k0 + ct * 16 + l16;
#pragma unroll
            for (int r = 0; r < 4; r++) {
                float v = s[ct][r] * sscale;
                if (diag) {
                    int row = q0 + wave * 16 + quad * 4 + r;
                    if (col > row) v = -1e30f;
                }
                sv[ct][r] = v;
            }
        }

        // tile row-max
        float vmax[4];
#pragma unroll
        for (int r = 0; r < 4; r++) {
            float v = fmaxf(fmaxf(sv[0][r], sv[1][r]), fmaxf(sv[2][r], sv[3][r]));
            v = fmaxf(v, __shfl_xor(v, 1));
            v = fmaxf(v, __shfl_xor(v, 2));
            v = fmaxf(v, __shfl_xor(v, 4));
            v = fmaxf(v, __shfl_xor(v, 8));
            vmax[r] = v;
        }
        // T13 defer-max: rescale only when some row grew by > 8 log2-units.
        float growth = fmaxf(fmaxf(vmax[0] - mrow[0], vmax[1] - mrow[1]),
                             fmaxf(vmax[2] - mrow[2], vmax[3] - mrow[3]));
        if (!__all(growth <= 8.0f)) {
            float alpha[4];
#pragma unroll
            for (int r = 0; r < 4; r++) {
                float mnew = fmaxf(mrow[r], vmax[r]);
                alpha[r] = exp2f(mrow[r] - mnew);
                mrow[r]  = mnew;
            }
#pragma unroll
            for (int j = 0; j < 8; j++)
#pragma unroll
                for (int r = 0; r < 4; r++) o[j][r] *= alpha[r];
#pragma unroll
            for (int r = 0; r < 4; r++) o9[r] *= alpha[r];
        }
        // P -> wave-private swizzled LDS: (row, col=ct*16+l16), chunk=ct*2+(l16>>3)
#pragma unroll
        for (int ct = 0; ct < 4; ct++) {
#pragma unroll
            for (int r = 0; r < 4; r++) {
                float p = exp2f(sv[ct][r] - mrow[r]);
                int row = quad * 4 + r;
                Ps[wave][row * 64 + (((ct * 2 + (l16 >> 3)) ^ (row & 7)) << 3) + (l16 & 7)] = f2bf(p);
            }
        }

        // PV + row-sum column (read logical chunk kk*4+quad of row l16)
        __builtin_amdgcn_s_setprio(1);
#pragma unroll
        for (int kk = 0; kk < 2; kk++) {
            bf16x8 pf = *(const bf16x8*)&Ps[wave][l16 * 64 + (((kk * 4 + quad) ^ (l16 & 7)) << 3)];
#pragma unroll
            for (int j = 0; j < 8; j++) {
                int vrow = j * 16 + l16;
                bf16x8 vf = *(const bf16x8*)&Vs[vrow * 64 + (((kk * 4 + quad) ^ (l16 & 7)) << 3)];
                o[j] = __builtin_amdgcn_mfma_f32_16x16x32_bf16(pf, vf, o[j], 0, 0, 0);
            }
            o9 = __builtin_amdgcn_mfma_f32_16x16x32_bf16(pf, ones, o9, 0, 0, 0);
        }
        __builtin_amdgcn_s_setprio(0);
    }

    // store partials: Po permuted layout [row][l16][j] -> 16B/lane full-line stores
    const size_t pidx = (size_t)b * NCH + c;
    const size_t pobase = pidx * (64 * 128);
    const size_t mbase  = pidx * 64;
#pragma unroll
    for (int r = 0; r < 4; r++) {
        int row = wave * 16 + quad * 4 + r;
        if (l16 == 0) { Pm[mbase + row] = mrow[r]; Pl[mbase + row] = o9[r]; }
        ushort8 val;
#pragma unroll
        for (int j = 0; j < 8; j++) val[j] = f2bf(o[j][r]);
        *(ushort8*)&Po[pobase + (size_t)row * 128 + l16 * 8] = val;
    }
}

// ---------------------------------------------------------------------------
// Combine n_ch(qt) <= 8 partials per (b,qt). grid (32, 8, 2), 32 q-rows/block.
// 16B ushort8 loads (permuted Po layout), dynamic s < n_ch loop. (R2 version.)
// ---------------------------------------------------------------------------
__global__ __launch_bounds__(256)
void combine(const unsigned short* __restrict__ Po, const float* __restrict__ Pm,
             const float* __restrict__ Pl, float* __restrict__ Out)
{
    const int qt = blockIdx.x, b = blockIdx.y, half = blockIdx.z;  // rows half*32..
    const int g = qt >> 2;
    const int n_ch = g + 1;
    const int cbase = 2 * g * (g + 1) + (qt - 4 * g) * (g + 1);
    const size_t p0 = (size_t)b * NCH + cbase;
    const int t = threadIdx.x;

    __shared__ float sw[8][32];    // [s][local row]
    __shared__ float sinv[32];

    if (t < 32) {
        int grow = half * 32 + t;
        float ms = -1e30f;
        for (int s = 0; s < n_ch; s++)
            ms = fmaxf(ms, Pm[(p0 + s) * 64 + grow]);
        float lsum = 0.0f;
        for (int s = 0; s < n_ch; s++) {
            float w = exp2f(Pm[(p0 + s) * 64 + grow] - ms);   // reload: L1-hot
            sw[s][t] = w;
            lsum += w * Pl[(p0 + s) * 64 + grow];
        }
        sinv[t] = 1.0f / lsum;
    }
    __syncthreads();

    float acc[2][8];
#pragma unroll
    for (int pass = 0; pass < 2; pass++)
#pragma unroll
        for (int j = 0; j < 8; j++) acc[pass][j] = 0.0f;

    for (int s = 0; s < n_ch; s++) {
        const size_t sbase = (p0 + s) * 8192;
#pragma unroll
        for (int pass = 0; pass < 2; pass++) {
            int cell = pass * 256 + t;
            int row = cell >> 4, l16g = cell & 15;
            int grow = half * 32 + row;
            float w = sw[s][row];
            ushort8 v = *(const ushort8*)&Po[sbase + (size_t)grow * 128 + l16g * 8];
#pragma unroll
            for (int j = 0; j < 8; j++) acc[pass][j] += w * bf2f(v[j]);
        }
    }

#pragma unroll
    for (int pass = 0; pass < 2; pass++) {
        int cell = pass * 256 + t;
        int row = cell >> 4, l16g = cell & 15;
        int grow = half * 32 + row;
        float inv = sinv[row];
        // Po slot (l16g, j) holds logical head-col j*16 + l16g
#pragma unroll
        for (int j = 0; j < 8; j++)
            Out[((size_t)b * SS + qt * 64 + grow) * HH + j * 16 + l16g] = acc[pass][j] * inv;
    }
}

extern "C" void kernel_launch(void* const* d_in, const int* in_sizes, int n_in,
                              void* d_out, int out_size, void* d_ws, size_t ws_size,
                              hipStream_t stream) {
    const float* X    = (const float*)d_in[0];
    const float* mask = (const float*)d_in[1];
    const float* Wq   = (const float*)d_in[2];
    const float* Wk   = (const float*)d_in[3];
    const float* Wv   = (const float*)d_in[4];

    char* ws = (char*)d_ws;
    // region A: Xb (25.2 MB) consumed by qkv_gemm, then reused as Po (18.9 MB)
    unsigned short* Xb = (unsigned short*)ws;
    unsigned short* Po = (unsigned short*)ws;
    ws += (size_t)MM * EE * 2;                                   // 25.17 MB
    unsigned short* Wb = (unsigned short*)ws; ws += (size_t)384 * EE * 2;
    unsigned short* Q  = (unsigned short*)ws; ws += (size_t)MM * HH * 2;
    unsigned short* Kb = (unsigned short*)ws; ws += (size_t)MM * HH * 2;
    unsigned short* Vt = (unsigned short*)ws; ws += (size_t)MM * HH * 2;
    float* Pm = (float*)ws; ws += (size_t)BB * NCH * 64 * 4;
    float* Pl = (float*)ws;

    cvt<<<1536 + 288, 256, 0, stream>>>(X, mask, Wq, Wk, Wv, Xb, Wb);
    qkv_gemm<<<768, 256, 0, stream>>>(Xb, Wb, Q, Kb, Vt);
    attn<<<1152, 256, 0, stream>>>(Q, Kb, Vt, Po, Pm, Pl);
    combine<<<dim3(NQT, BB, 2), 256, 0, stream>>>(Po, Pm, Pl, (float*)d_out);
}